// Round 12
// baseline (324.852 us; speedup 1.0000x reference)
//
#include <hip/hip_runtime.h>

// DeepComplexRBF as 6 plain kernels in the captured graph (one per phase).
//   dist_sq[i] = sum_j |y[j] - G[i,j]|^2 ; phi[i] = exp(-dist_sq/(2 s[i]))
//   y_new[o]   = sum_i W[o,i]*phi[i] + b[o]
// 576 MB of G/W streamed once; ~280 MB L3-hit per replay (FETCH ~296 MB).
//
// r6=119.3 r8=118.2 (ILP ok) r10=124.9 (LDS staging regress)
// r11=112.1 (block-per-row, 4x static oversubscription -> tail theory
// CONFIRMED). r12: endpoint of that theory = dynamic ticket scheduling.
// 1024 persistent blocks/kernel grab rows via atomicAdd on a per-kernel
// counter (memset node zeroes 6 counters each call; row results are
// order-independent -> bit-deterministic). Drain ramp ~1 row. phi1 gets
// wave-per-row tickets (4 rows/ticket, B=4) fixing its 1-float4 ILP.

#define D0 1024
#define H  4096
#define NPB 1024   // persistent blocks per kernel

__device__ __forceinline__ float wave_sum(float v) {
#pragma unroll
    for (int off = 32; off > 0; off >>= 1) v += __shfl_down(v, off, 64);
    return v;
}

// phi[row] = exp(-|y - G[row]|^2 / (2 s[row])); G (2, ROWS, COLS),
// y2 = 2*COLS contiguous (re plane, im plane).
// COLS>=4096: block-per-row, wave w owns quarter w.
// COLS==1024: wave-per-row, ticket covers 4 rows.
template <int COLS, int ROWS>
__global__ __launch_bounds__(256, 4) void phi_tk(
        const float* __restrict__ G, const float* __restrict__ y2,
        const float* __restrict__ sv, float* __restrict__ phi,
        int* __restrict__ tk) {
    const int lane = threadIdx.x & 63;
    const int w = threadIdx.x >> 6;
    __shared__ int stk;
    __shared__ float sred[4];

    if constexpr (COLS >= 4096) {
        constexpr int QL = COLS / 4;     // floats per wave per plane
        constexpr int NIT = QL / 256;    // 4
        constexpr int B = 4;
        for (;;) {
            if (threadIdx.x == 0) stk = atomicAdd(tk, 1);
            __syncthreads();
            const int row = stk;
            if (row >= ROWS) return;
            const float* gre = G + (size_t)row * COLS + w * QL;
            const float* gim = gre + (size_t)ROWS * COLS;
            float acc = 0.f;
#pragma unroll
            for (int pl = 0; pl < 2; ++pl) {
                const float* gp = pl ? gim : gre;
                const float* yp = y2 + pl * COLS + w * QL;
#pragma unroll
                for (int it0 = 0; it0 < NIT; it0 += B) {
                    float4 g[B], y[B];
#pragma unroll
                    for (int u = 0; u < B; ++u) {
                        const int j = lane * 4 + (it0 + u) * 256;
                        g[u] = *(const float4*)(gp + j);
                        y[u] = *(const float4*)(yp + j);
                    }
#pragma unroll
                    for (int u = 0; u < B; ++u) {
                        float d;
                        d = y[u].x - g[u].x; acc += d * d;
                        d = y[u].y - g[u].y; acc += d * d;
                        d = y[u].z - g[u].z; acc += d * d;
                        d = y[u].w - g[u].w; acc += d * d;
                    }
                }
            }
            acc = wave_sum(acc);
            if (lane == 0) sred[w] = acc;
            __syncthreads();
            if (threadIdx.x == 0) {
                const float d = (sred[0] + sred[1]) + (sred[2] + sred[3]);
                phi[row] = expf(-d / (2.0f * sv[row]));
            }
            __syncthreads();   // stk/sred safe for reuse
        }
    } else {
        // wave-per-row: ticket t covers rows 4t..4t+3, wave w takes 4t+w
        constexpr int NIT = COLS / 256;  // 4
        constexpr int B = 4;
        for (;;) {
            if (threadIdx.x == 0) stk = atomicAdd(tk, 1);
            __syncthreads();
            const int t = stk;
            __syncthreads();   // all waves read before next overwrite
            if (t * 4 >= ROWS) return;
            const int row = t * 4 + w;
            const float* gre = G + (size_t)row * COLS;
            const float* gim = gre + (size_t)ROWS * COLS;
            float acc = 0.f;
#pragma unroll
            for (int pl = 0; pl < 2; ++pl) {
                const float* gp = pl ? gim : gre;
                const float* yp = y2 + pl * COLS;
#pragma unroll
                for (int it0 = 0; it0 < NIT; it0 += B) {
                    float4 g[B], y[B];
#pragma unroll
                    for (int u = 0; u < B; ++u) {
                        const int j = lane * 4 + (it0 + u) * 256;
                        g[u] = *(const float4*)(gp + j);
                        y[u] = *(const float4*)(yp + j);
                    }
#pragma unroll
                    for (int u = 0; u < B; ++u) {
                        float d;
                        d = y[u].x - g[u].x; acc += d * d;
                        d = y[u].y - g[u].y; acc += d * d;
                        d = y[u].z - g[u].z; acc += d * d;
                        d = y[u].w - g[u].w; acc += d * d;
                    }
                }
            }
            acc = wave_sum(acc);
            if (lane == 0) phi[row] = expf(-acc / (2.0f * sv[row]));
        }
    }
}

// (ore,oim)[row] = W[row] . phi + b[row]; W (2, ROWS, COLS), bias (2, ROWS).
// Block-per-row, wave w owns quarter w; dynamic tickets.
template <int COLS, int ROWS>
__global__ __launch_bounds__(256, 4) void w_tk(
        const float* __restrict__ W, const float* __restrict__ bias,
        const float* __restrict__ phi,
        float* __restrict__ ore, float* __restrict__ oim,
        int* __restrict__ tk) {
    const int lane = threadIdx.x & 63;
    const int w = threadIdx.x >> 6;
    constexpr int QL = COLS / 4;
    constexpr int NIT = QL / 256;        // 4
    constexpr int B = 4;
    __shared__ int stk;
    __shared__ float sred[8];

    for (;;) {
        if (threadIdx.x == 0) stk = atomicAdd(tk, 1);
        __syncthreads();
        const int row = stk;
        if (row >= ROWS) return;
        const float* wre = W + (size_t)row * COLS + w * QL;
        const float* wim = wre + (size_t)ROWS * COLS;
        const float* ph0 = phi + w * QL;
        float ac[2] = {0.f, 0.f};
#pragma unroll
        for (int pl = 0; pl < 2; ++pl) {
            const float* mp = pl ? wim : wre;
            float a = 0.f;
#pragma unroll
            for (int it0 = 0; it0 < NIT; it0 += B) {
                float4 m[B], p[B];
#pragma unroll
                for (int u = 0; u < B; ++u) {
                    const int j = lane * 4 + (it0 + u) * 256;
                    m[u] = *(const float4*)(mp + j);
                    p[u] = *(const float4*)(ph0 + j);
                }
#pragma unroll
                for (int u = 0; u < B; ++u)
                    a += m[u].x * p[u].x + m[u].y * p[u].y
                       + m[u].z * p[u].z + m[u].w * p[u].w;
            }
            ac[pl] = a;
        }
        const float ar = wave_sum(ac[0]);
        const float ai = wave_sum(ac[1]);
        if (lane == 0) { sred[w] = ar; sred[4 + w] = ai; }
        __syncthreads();
        if (threadIdx.x == 0) {
            ore[row] = (sred[0] + sred[1]) + (sred[2] + sred[3]) + bias[row];
            oim[row] = (sred[4] + sred[5]) + (sred[6] + sred[7]) + bias[ROWS + row];
        }
        __syncthreads();   // stk/sred safe for reuse
    }
}

extern "C" void kernel_launch(void* const* d_in, const int* in_sizes, int n_in,
                              void* d_out, int out_size, void* d_ws, size_t ws_size,
                              hipStream_t stream) {
    const float* x  = (const float*)d_in[0];
    const float* W1 = (const float*)d_in[1];
    const float* b1 = (const float*)d_in[2];
    const float* G1 = (const float*)d_in[3];
    const float* s1 = (const float*)d_in[4];
    const float* W2 = (const float*)d_in[5];
    const float* b2 = (const float*)d_in[6];
    const float* G2 = (const float*)d_in[7];
    const float* s2 = (const float*)d_in[8];
    const float* W3 = (const float*)d_in[9];
    const float* b3 = (const float*)d_in[10];
    const float* G3 = (const float*)d_in[11];
    const float* s3 = (const float*)d_in[12];
    float* out = (float*)d_out;   // (2, 1024)

    float* ws  = (float*)d_ws;
    float* phi = ws;              // 4096
    float* y2  = ws + H;          // 8192: y re plane then im plane (contig)
    int* tk = (int*)(ws + 16384); // 6 ticket counters, 64 B apart

    // zero the 6 ticket counters each (graph-replayed) call
    hipMemsetAsync(tk, 0, 6 * 16 * sizeof(int), stream);

    // Layer 1 (x is (2, D0) contiguous = re plane then im plane)
    phi_tk<D0, H><<<NPB, 256, 0, stream>>>(G1, x, s1, phi, tk);
    w_tk<H, H><<<NPB, 256, 0, stream>>>(W1, b1, phi, y2, y2 + H, tk + 16);
    // Layer 2
    phi_tk<H, H><<<NPB, 256, 0, stream>>>(G2, y2, s2, phi, tk + 32);
    w_tk<H, H><<<NPB, 256, 0, stream>>>(W2, b2, phi, y2, y2 + H, tk + 48);
    // Layer 3
    phi_tk<H, H><<<NPB, 256, 0, stream>>>(G3, y2, s3, phi, tk + 64);
    w_tk<H, D0><<<NPB, 256, 0, stream>>>(W3, b3, phi, out, out + D0, tk + 80);
}

// Round 13
// 110.849 us; speedup vs baseline: 2.9306x; 2.9306x over previous
//
#include <hip/hip_runtime.h>

// DeepComplexRBF as 6 plain kernels in the captured graph (one per phase).
//   dist_sq[i] = sum_j |y[j] - G[i,j]|^2 ; phi[i] = exp(-dist_sq/(2 s[i]))
//   y_new[o]   = sum_i W[o,i]*phi[i] + b[o]
// 576 MB of G/W streamed once; ~280 MB L3-hit per replay (FETCH ~296 MB).
//
// r6=119.3  r8=118.2 (ILP fine)  r10=124.9 (LDS staging regress)
// r11=112.1 BEST (block-per-row, 4x grid oversubscription: the HW
// dispatcher dynamically refills retiring blocks = free load balancing)
// r12=324.9 (software tickets: 4096 hot-line atomics/kernel ~35us/kernel
// REGRESSION -- dispatcher already does this for free).
// r13 = r11 + phi1 ILP fix: COLS==1024 had B=1 (one float4/plane in
// flight). Now wave-per-row for COLS==1024: block covers rows 4b..4b+3,
// each wave a full row (NIT=4, B=4 -> 8 loads in flight).

#define D0 1024
#define H  4096

__device__ __forceinline__ float wave_sum(float v) {
#pragma unroll
    for (int off = 32; off > 0; off >>= 1) v += __shfl_down(v, off, 64);
    return v;
}

// phi[row] = exp(-|y - G[row]|^2 / (2 s[row])); G (2, ROWS, COLS),
// y2 = 2*COLS contiguous (re plane, im plane).
// COLS>=4096: block-per-row (grid=ROWS), wave w owns quarter w.
// COLS==1024: wave-per-row (grid=ROWS/4), wave w owns row 4b+w.
template <int COLS, int ROWS>
__global__ __launch_bounds__(256, 4) void phi_k(
        const float* __restrict__ G, const float* __restrict__ y2,
        const float* __restrict__ sv, float* __restrict__ phi) {
    const int lane = threadIdx.x & 63;
    const int w = threadIdx.x >> 6;

    if constexpr (COLS >= 4096) {
        constexpr int QL = COLS / 4;     // floats per wave per plane
        constexpr int NIT = QL / 256;    // 4
        constexpr int B = 4;
        const int row = blockIdx.x;
        const float* gre = G + (size_t)row * COLS + w * QL;
        const float* gim = gre + (size_t)ROWS * COLS;
        float acc = 0.f;
#pragma unroll
        for (int pl = 0; pl < 2; ++pl) {
            const float* gp = pl ? gim : gre;
            const float* yp = y2 + pl * COLS + w * QL;
#pragma unroll
            for (int it0 = 0; it0 < NIT; it0 += B) {
                float4 g[B], y[B];
#pragma unroll
                for (int u = 0; u < B; ++u) {
                    const int j = lane * 4 + (it0 + u) * 256;
                    g[u] = *(const float4*)(gp + j);
                    y[u] = *(const float4*)(yp + j);
                }
#pragma unroll
                for (int u = 0; u < B; ++u) {
                    float d;
                    d = y[u].x - g[u].x; acc += d * d;
                    d = y[u].y - g[u].y; acc += d * d;
                    d = y[u].z - g[u].z; acc += d * d;
                    d = y[u].w - g[u].w; acc += d * d;
                }
            }
        }
        acc = wave_sum(acc);
        __shared__ float sred[4];
        if (lane == 0) sred[w] = acc;
        __syncthreads();
        if (threadIdx.x == 0) {
            const float d = (sred[0] + sred[1]) + (sred[2] + sred[3]);
            phi[row] = expf(-d / (2.0f * sv[row]));
        }
    } else {
        // wave-per-row: row = 4*blockIdx + w; full row per wave
        constexpr int NIT = COLS / 256;  // 4
        constexpr int B = 4;
        const int row = blockIdx.x * 4 + w;
        const float* gre = G + (size_t)row * COLS;
        const float* gim = gre + (size_t)ROWS * COLS;
        float acc = 0.f;
#pragma unroll
        for (int pl = 0; pl < 2; ++pl) {
            const float* gp = pl ? gim : gre;
            const float* yp = y2 + pl * COLS;
#pragma unroll
            for (int it0 = 0; it0 < NIT; it0 += B) {
                float4 g[B], y[B];
#pragma unroll
                for (int u = 0; u < B; ++u) {
                    const int j = lane * 4 + (it0 + u) * 256;
                    g[u] = *(const float4*)(gp + j);
                    y[u] = *(const float4*)(yp + j);
                }
#pragma unroll
                for (int u = 0; u < B; ++u) {
                    float d;
                    d = y[u].x - g[u].x; acc += d * d;
                    d = y[u].y - g[u].y; acc += d * d;
                    d = y[u].z - g[u].z; acc += d * d;
                    d = y[u].w - g[u].w; acc += d * d;
                }
            }
        }
        acc = wave_sum(acc);
        if (lane == 0) phi[row] = expf(-acc / (2.0f * sv[row]));
    }
}

// (ore,oim)[row] = W[row] . phi + b[row]; W (2, ROWS, COLS), bias (2, ROWS).
// Block-per-row (grid=ROWS), wave w owns quarter w.
template <int COLS, int ROWS>
__global__ __launch_bounds__(256, 4) void w_k(
        const float* __restrict__ W, const float* __restrict__ bias,
        const float* __restrict__ phi,
        float* __restrict__ ore, float* __restrict__ oim) {
    const int lane = threadIdx.x & 63;
    const int w = threadIdx.x >> 6;
    const int row = blockIdx.x;
    constexpr int QL = COLS / 4;
    constexpr int NIT = QL / 256;        // 4
    constexpr int B = 4;

    const float* wre = W + (size_t)row * COLS + w * QL;
    const float* wim = wre + (size_t)ROWS * COLS;
    const float* ph0 = phi + w * QL;

    float ac[2] = {0.f, 0.f};
#pragma unroll
    for (int pl = 0; pl < 2; ++pl) {
        const float* mp = pl ? wim : wre;
        float a = 0.f;
#pragma unroll
        for (int it0 = 0; it0 < NIT; it0 += B) {
            float4 m[B], p[B];
#pragma unroll
            for (int u = 0; u < B; ++u) {
                const int j = lane * 4 + (it0 + u) * 256;
                m[u] = *(const float4*)(mp + j);
                p[u] = *(const float4*)(ph0 + j);
            }
#pragma unroll
            for (int u = 0; u < B; ++u)
                a += m[u].x * p[u].x + m[u].y * p[u].y
                   + m[u].z * p[u].z + m[u].w * p[u].w;
        }
        ac[pl] = a;
    }
    const float ar = wave_sum(ac[0]);
    const float ai = wave_sum(ac[1]);
    __shared__ float sred[8];
    if (lane == 0) { sred[w] = ar; sred[4 + w] = ai; }
    __syncthreads();
    if (threadIdx.x == 0) {
        ore[row] = (sred[0] + sred[1]) + (sred[2] + sred[3]) + bias[row];
        oim[row] = (sred[4] + sred[5]) + (sred[6] + sred[7]) + bias[ROWS + row];
    }
}

extern "C" void kernel_launch(void* const* d_in, const int* in_sizes, int n_in,
                              void* d_out, int out_size, void* d_ws, size_t ws_size,
                              hipStream_t stream) {
    const float* x  = (const float*)d_in[0];
    const float* W1 = (const float*)d_in[1];
    const float* b1 = (const float*)d_in[2];
    const float* G1 = (const float*)d_in[3];
    const float* s1 = (const float*)d_in[4];
    const float* W2 = (const float*)d_in[5];
    const float* b2 = (const float*)d_in[6];
    const float* G2 = (const float*)d_in[7];
    const float* s2 = (const float*)d_in[8];
    const float* W3 = (const float*)d_in[9];
    const float* b3 = (const float*)d_in[10];
    const float* G3 = (const float*)d_in[11];
    const float* s3 = (const float*)d_in[12];
    float* out = (float*)d_out;   // (2, 1024)

    float* ws  = (float*)d_ws;
    float* phi = ws;              // 4096
    float* y2  = ws + H;          // 8192: y re plane then im plane (contig)
    // no init needed: phi/y fully written before first read each call

    // Layer 1 (x is (2, D0) contiguous = re plane then im plane)
    phi_k<D0, H><<<H / 4, 256, 0, stream>>>(G1, x, s1, phi);
    w_k<H, H><<<H, 256, 0, stream>>>(W1, b1, phi, y2, y2 + H);
    // Layer 2
    phi_k<H, H><<<H, 256, 0, stream>>>(G2, y2, s2, phi);
    w_k<H, H><<<H, 256, 0, stream>>>(W2, b2, phi, y2, y2 + H);
    // Layer 3
    phi_k<H, H><<<H, 256, 0, stream>>>(G3, y2, s3, phi);
    w_k<H, D0><<<D0, 256, 0, stream>>>(W3, b3, phi, out, out + D0);
}